// Round 4
// baseline (211.552 us; speedup 1.0000x reference)
//
#include <hip/hip_runtime.h>
#include <cstdint>

#define BATCH  4
#define SLEN   4096
#define FDIM   64
#define KDIM   32
#define KSPLIT 4
#define CHUNK  (SLEN / KSPLIT)   // 1024
#define NSTEP  (CHUNK / 64)      // 16 (64 keys per step)
#define VSTRIDE 76               // shorts; 152B row stride -> 2-way banks on b64
#define NQBLK  (SLEN / 128)      // 32

// sqrt(log2(e)): M is pre-scaled so QK^T scores come out log2e-scaled and
// exp(relu(s)) == exp2(relu(s_scaled)) -> bare v_exp_f32.
#define MSCALE 1.2011224087864498f

typedef __attribute__((ext_vector_type(8))) short bf16x8;
typedef __attribute__((ext_vector_type(4))) short bf16x4;
typedef __attribute__((ext_vector_type(4))) float f32x4;

#if __has_builtin(__builtin_amdgcn_exp2f)
#define EXP2(x) __builtin_amdgcn_exp2f(x)
#else
#define EXP2(x) exp2f(x)
#endif

static __device__ __forceinline__ short f2bf(float f) {
    union { float f; unsigned u; } v; v.f = f;
    unsigned r = v.u + 0x7fffu + ((v.u >> 16) & 1u);   // RNE
    return (short)(r >> 16);
}
static __device__ __forceinline__ float bf2f(short s) {
    union { unsigned u; float f; } v;
    v.u = ((unsigned)(unsigned short)s) << 16;
    return v.f;
}
// HW packed f32->bf16 (RNE), 1 instruction: lo16 = bf16(a), hi16 = bf16(b).
static __device__ __forceinline__ unsigned cvt_pk_bf16(float a, float b) {
    unsigned r;
    asm("v_cvt_pk_bf16_f32 %0, %1, %2" : "=v"(r) : "v"(a), "v"(b));
    return r;
}

// ---------------------------------------------------------------------------
// Fused prep: (a) M*MSCALE -> bf16 hi/lo Dekker split, (b) V = X@W (fp32),
// (c) Vt[b][f][s] = bf16(V[b][s][f]), (d) block 0 zeroes the split-K
// arrival counters (workspace is poisoned every iteration; counters are
// additionally self-resetting inside attn for replay robustness).
// Grid (256,4) = 1024 blocks.
// ---------------------------------------------------------------------------
__global__ __launch_bounds__(256) void prep(const float4* __restrict__ M4,
                                            ushort4* __restrict__ H4,
                                            ushort4* __restrict__ L4,
                                            const float4* __restrict__ X4,
                                            const float4* __restrict__ W4,
                                            float4* __restrict__ V4,
                                            short* __restrict__ Vt,
                                            unsigned* __restrict__ cnt) {
    const int tid = threadIdx.x;
    const int blk = blockIdx.y * gridDim.x + blockIdx.x;   // 0..1023
    if (blk == 0 && tid < BATCH * NQBLK) cnt[tid] = 0;     // 128 counters
    // --- (a) scaled split of M: 1 float4 per thread, first 512 blocks ---
    if (blk < (BATCH * SLEN * KDIM) / (4 * 256)) {         // 512
        int i = blk * 256 + tid;
        float4 m = M4[i];
        float mx = m.x * MSCALE, my = m.y * MSCALE;
        float mz = m.z * MSCALE, mw = m.w * MSCALE;
        ushort4 h, l;
        h.x = (unsigned short)f2bf(mx); l.x = (unsigned short)f2bf(mx - bf2f((short)h.x));
        h.y = (unsigned short)f2bf(my); l.y = (unsigned short)f2bf(my - bf2f((short)h.y));
        h.z = (unsigned short)f2bf(mz); l.z = (unsigned short)f2bf(mz - bf2f((short)h.z));
        h.w = (unsigned short)f2bf(mw); l.w = (unsigned short)f2bf(mw - bf2f((short)h.w));
        H4[i] = h; L4[i] = l;
    }
    // --- (b)+(c) XW + transpose: 16 rows per block ---
    __shared__ float t[16][68];
    const int b  = blockIdx.y;
    const int s0 = blockIdx.x * 16;
    const int r  = tid >> 4;                               // 0..15
    const int o4 = tid & 15;
    const float4* __restrict__ xr = X4 + ((size_t)b * SLEN + s0 + r) * (FDIM / 4);
    float4 acc = make_float4(0.f, 0.f, 0.f, 0.f);
#pragma unroll
    for (int f4 = 0; f4 < FDIM / 4; ++f4) {
        float4 x  = xr[f4];
        float4 w0 = W4[(f4 * 4 + 0) * 16 + o4];
        float4 w1 = W4[(f4 * 4 + 1) * 16 + o4];
        float4 w2 = W4[(f4 * 4 + 2) * 16 + o4];
        float4 w3 = W4[(f4 * 4 + 3) * 16 + o4];
        acc.x = fmaf(x.x, w0.x, fmaf(x.y, w1.x, fmaf(x.z, w2.x, fmaf(x.w, w3.x, acc.x))));
        acc.y = fmaf(x.x, w0.y, fmaf(x.y, w1.y, fmaf(x.z, w2.y, fmaf(x.w, w3.y, acc.y))));
        acc.z = fmaf(x.x, w0.z, fmaf(x.y, w1.z, fmaf(x.z, w2.z, fmaf(x.w, w3.z, acc.z))));
        acc.w = fmaf(x.x, w0.w, fmaf(x.y, w1.w, fmaf(x.z, w2.w, fmaf(x.w, w3.w, acc.w))));
    }
    V4[((size_t)b * SLEN + s0 + r) * 16 + o4] = acc;
    t[r][o4 * 4 + 0] = acc.x;
    t[r][o4 * 4 + 1] = acc.y;
    t[r][o4 * 4 + 2] = acc.z;
    t[r][o4 * 4 + 3] = acc.w;
    __syncthreads();
    const int c  = tid & 15;
    const int f0 = tid >> 4;
#pragma unroll
    for (int i2 = 0; i2 < 4; ++i2) {
        int f = f0 + i2 * 16;
        Vt[((size_t)b * FDIM + f) * SLEN + s0 + c] = f2bf(t[c][f]);
    }
}

// ---------------------------------------------------------------------------
// Attention + fused split-K combine. 512 blocks (2/CU), 4 waves, 128 q/block,
// 64 keys/step, double-buffered LDS, ONE raw s_barrier per step (no vmcnt
// drain), prefetch in flight across barriers.
// Epilogue: write partial (accP[pbq][ks][128][64], lP[pbq][128][ks]),
// release-fence, acq_rel arrival increment; the 4th-arriving block re-reads
// all 4 partials (L3-hot, fixed ks order -> deterministic sum), writes
// out = V + acc/l + bias directly, then RESETS the counter (replay-safe).
// ---------------------------------------------------------------------------
__global__ __launch_bounds__(256, 2) void attn_mfma(const short* __restrict__ Mhi,
                                                    const short* __restrict__ Mlo,
                                                    const short* __restrict__ Vt,
                                                    float* __restrict__ accP,
                                                    float* __restrict__ lP,
                                                    unsigned* __restrict__ cnt,
                                                    const float4* __restrict__ V4,
                                                    const float4* __restrict__ bias4,
                                                    float4* __restrict__ out4) {
    const int bid  = blockIdx.x;                 // 512 blocks
    const int slab = (bid & 7) + 8 * (bid >> 8); // 0..15, XCD-local
    const int qblk = (bid >> 3) & 31;
    const int b    = slab >> 2;
    const int ks   = slab & 3;
    const int pbq  = b * NQBLK + qblk;           // 0..127

    const int tid  = threadIdx.x;
    const int wave = tid >> 6;
    const int lane = tid & 63;
    const int col  = lane & 15;
    const int quad = lane >> 4;
    const int qbase = qblk * 128 + wave * 32;
    const int k0    = ks * CHUNK;

    const short* __restrict__ Mbh = Mhi + (size_t)b * SLEN * KDIM;
    const short* __restrict__ Mbl = Mlo + (size_t)b * SLEN * KDIM;
    const short* __restrict__ Vb  = Vt  + (size_t)b * FDIM * SLEN;

    __shared__ short khi[2][64 * 40];            // key rows, 80 B stride
    __shared__ short klo[2][64 * 40];
    __shared__ short vsh[2][64 * VSTRIDE];       // f rows, 152 B stride
    __shared__ int lastflag;

    // Q fragments (B-operand: n = q = col, k = quad*8+j).
    bf16x8 Qh[2], Ql[2];
#pragma unroll
    for (int tq = 0; tq < 2; ++tq) {
        int qo = (qbase + tq * 16 + col) * KDIM + quad * 8;
        Qh[tq] = *(const bf16x8*)(Mbh + qo);
        Ql[tq] = *(const bf16x8*)(Mbl + qo);
    }

    f32x4 accf[2][4];
#pragma unroll
    for (int tq = 0; tq < 2; ++tq)
#pragma unroll
        for (int fg = 0; fg < 4; ++fg) accf[tq][fg] = (f32x4){0.f, 0.f, 0.f, 0.f};
    float lacc[2] = {0.f, 0.f};

    // Staging: tid<128 -> khi, else klo; each thread 2x16B. V: 2x16B each.
    const int krow = (tid & 127) >> 1;           // 0..63
    const int kp   = tid & 1;
    const int vrow = tid >> 2;                   // 0..63
    const int vp   = tid & 3;
    const short* __restrict__ Msrc = (tid < 128) ? Mbh : Mbl;
    const int kg0 = krow * KDIM + (kp * 2 + 0) * 8;
    const int kg1 = krow * KDIM + (kp * 2 + 1) * 8;
    const int kl0 = krow * 40 + (kp * 2 + 0) * 8;
    const int kl1 = krow * 40 + (kp * 2 + 1) * 8;
    const int vl0 = vrow * VSTRIDE + (vp + 0) * 8;
    const int vl1 = vrow * VSTRIDE + (vp + 4) * 8;

    // Prologue loads for step 0.
    bf16x8 ksA = *(const bf16x8*)(Msrc + (size_t)k0 * KDIM + kg0);
    bf16x8 ksB = *(const bf16x8*)(Msrc + (size_t)k0 * KDIM + kg1);
    bf16x8 vsA = *(const bf16x8*)(Vb + (size_t)vrow * SLEN + k0 + (vp + 0) * 8);
    bf16x8 vsB = *(const bf16x8*)(Vb + (size_t)vrow * SLEN + k0 + (vp + 4) * 8);

#pragma unroll 1
    for (int step = 0; step < NSTEP; ++step) {
        const int cur = step & 1;
        short* __restrict__ kdst = (tid < 128) ? khi[cur] : klo[cur];
        *(bf16x8*)(kdst + kl0)     = ksA;        // waits vmcnt for own loads
        *(bf16x8*)(kdst + kl1)     = ksB;
        *(bf16x8*)(vsh[cur] + vl0) = vsA;
        *(bf16x8*)(vsh[cur] + vl1) = vsB;
        if (step + 1 < NSTEP) {                  // next-step loads fly across
            int kt = k0 + (step + 1) * 64;       // the barrier
            ksA = *(const bf16x8*)(Msrc + (size_t)kt * KDIM + kg0);
            ksB = *(const bf16x8*)(Msrc + (size_t)kt * KDIM + kg1);
            vsA = *(const bf16x8*)(Vb + (size_t)vrow * SLEN + kt + (vp + 0) * 8);
            vsB = *(const bf16x8*)(Vb + (size_t)vrow * SLEN + kt + (vp + 4) * 8);
        }
        asm volatile("s_waitcnt lgkmcnt(0)" ::: "memory");  // ds_writes visible
        __builtin_amdgcn_s_barrier();                       // NO vmcnt drain
        __builtin_amdgcn_sched_barrier(0);

        const short* __restrict__ kh = khi[cur];
        const short* __restrict__ kl = klo[cur];
        const short* __restrict__ vv = vsh[cur];

        // K A-frags: tile t = keys t*16..t*16+15, m = col within tile.
        bf16x8 Kh[4], Kl[4];
#pragma unroll
        for (int t = 0; t < 4; ++t) {
            Kh[t] = *(const bf16x8*)(kh + (t * 16 + col) * 40 + quad * 8);
            Kl[t] = *(const bf16x8*)(kl + (t * 16 + col) * 40 + quad * 8);
        }
        // V B-frags per fg, key-group g (32 keys).
        bf16x8 Vg[4][2];
#pragma unroll
        for (int fg = 0; fg < 4; ++fg)
#pragma unroll
            for (int g = 0; g < 2; ++g) {
                const short* vp_ = vv + (fg * 16 + col) * VSTRIDE + g * 32 + quad * 4;
                bf16x4 vlo = *(const bf16x4*)(vp_);
                bf16x4 vhi = *(const bf16x4*)(vp_ + 16);
                Vg[fg][g] = __builtin_shufflevector(vlo, vhi, 0, 1, 2, 3, 4, 5, 6, 7);
            }

        __builtin_amdgcn_s_setprio(1);
#pragma unroll
        for (int tq = 0; tq < 2; ++tq) {
            f32x4 c[4];
#pragma unroll
            for (int t = 0; t < 4; ++t) {
                f32x4 z = (f32x4){0.f, 0.f, 0.f, 0.f};
                c[t] = __builtin_amdgcn_mfma_f32_16x16x32_bf16(Kh[t], Ql[tq], z, 0, 0, 0);
                c[t] = __builtin_amdgcn_mfma_f32_16x16x32_bf16(Kl[t], Qh[tq], c[t], 0, 0, 0);
                c[t] = __builtin_amdgcn_mfma_f32_16x16x32_bf16(Kh[t], Qh[tq], c[t], 0, 0, 0);
            }
            float e[16];
#pragma unroll
            for (int t = 0; t < 4; ++t) {
                e[t * 4 + 0] = EXP2(fmaxf(c[t][0], 0.f));
                e[t * 4 + 1] = EXP2(fmaxf(c[t][1], 0.f));
                e[t * 4 + 2] = EXP2(fmaxf(c[t][2], 0.f));
                e[t * 4 + 3] = EXP2(fmaxf(c[t][3], 0.f));
            }
            lacc[tq] += (((e[0] + e[1]) + (e[2] + e[3])) + ((e[4] + e[5]) + (e[6] + e[7])))
                      + (((e[8] + e[9]) + (e[10] + e[11])) + ((e[12] + e[13]) + (e[14] + e[15])));

            union { unsigned u[4]; bf16x8 v; } pa0, pa1;
            pa0.u[0] = cvt_pk_bf16(e[0],  e[1]);
            pa0.u[1] = cvt_pk_bf16(e[2],  e[3]);
            pa0.u[2] = cvt_pk_bf16(e[4],  e[5]);
            pa0.u[3] = cvt_pk_bf16(e[6],  e[7]);
            pa1.u[0] = cvt_pk_bf16(e[8],  e[9]);
            pa1.u[1] = cvt_pk_bf16(e[10], e[11]);
            pa1.u[2] = cvt_pk_bf16(e[12], e[13]);
            pa1.u[3] = cvt_pk_bf16(e[14], e[15]);

#pragma unroll
            for (int fg = 0; fg < 4; ++fg) {
                accf[tq][fg] = __builtin_amdgcn_mfma_f32_16x16x32_bf16(
                    pa0.v, Vg[fg][0], accf[tq][fg], 0, 0, 0);
                accf[tq][fg] = __builtin_amdgcn_mfma_f32_16x16x32_bf16(
                    pa1.v, Vg[fg][1], accf[tq][fg], 0, 0, 0);
            }
        }
        __builtin_amdgcn_s_setprio(0);
    }

    // --- Partial store: accP[pbq][ks][128][64], lP[pbq][128][ks] ---
    float* __restrict__ myP = accP + ((size_t)pbq * KSPLIT + ks) * (128 * 64);
#pragma unroll
    for (int tq = 0; tq < 2; ++tq) {
#pragma unroll
        for (int j = 0; j < 4; ++j) {
            int ql = wave * 32 + tq * 16 + quad * 4 + j;
            float* __restrict__ op = myP + ql * 64;
#pragma unroll
            for (int fg = 0; fg < 4; ++fg)
                op[fg * 16 + col] = accf[tq][fg][j];
        }
        float lv = lacc[tq];
        lv += __shfl_xor(lv, 16);
        lv += __shfl_xor(lv, 32);
        if (quad == 0) {
            int ql = wave * 32 + tq * 16 + col;
            lP[((size_t)pbq * 128 + ql) * KSPLIT + ks] = lv;
        }
    }

    // --- Split-K rendezvous: 4th arrival does the combine ---
    __threadfence();                              // release partial stores
    __syncthreads();                              // all waves' stores fenced
    if (tid == 0) {
        unsigned prev = __hip_atomic_fetch_add(&cnt[pbq], 1u,
                                               __ATOMIC_ACQ_REL,
                                               __HIP_MEMORY_SCOPE_AGENT);
        lastflag = (prev == KSPLIT - 1);
    }
    __syncthreads();
    if (lastflag) {
        __threadfence();                          // acquire partner stores
        const float4* __restrict__ Pp  = (const float4*)(accP + (size_t)pbq * KSPLIT * (128 * 64));
        const float4* __restrict__ lp4 = (const float4*)(lP + (size_t)pbq * 128 * KSPLIT);
#pragma unroll
        for (int t = 0; t < 8; ++t) {
            int i  = t * 256 + tid;               // 0..2047
            int o4 = i & 15;
            int ql = i >> 4;                      // 0..127
            float4 l = lp4[ql];
            float r = 1.f / ((l.x + l.y) + (l.z + l.w));
            float nx = 0.f, ny = 0.f, nz = 0.f, nw = 0.f;
#pragma unroll
            for (int k2 = 0; k2 < KSPLIT; ++k2) {
                float4 a = Pp[((size_t)k2 * 128 + ql) * 16 + o4];
                nx += a.x; ny += a.y; nz += a.z; nw += a.w;
            }
            size_t gi = ((size_t)b * SLEN + qblk * 128 + ql) * 16 + o4;
            float4 v  = V4[gi];
            float4 bb = bias4[o4];
            float4 o;
            o.x = v.x + nx * r + bb.x;
            o.y = v.y + ny * r + bb.y;
            o.z = v.z + nz * r + bb.z;
            o.w = v.w + nw * r + bb.w;
            out4[gi] = o;
        }
        // Self-reset: counter returns to 0 at end of every attn execution,
        // making the rendezvous robust to any replay granularity.
        if (tid == 0)
            __hip_atomic_store(&cnt[pbq], 0u, __ATOMIC_RELAXED,
                               __HIP_MEMORY_SCOPE_AGENT);
    }
}

// ---------------------------------------------------------------------------
extern "C" void kernel_launch(void* const* d_in, const int* in_sizes, int n_in,
                              void* d_out, int out_size, void* d_ws, size_t ws_size,
                              hipStream_t stream) {
    const float* X    = (const float*)d_in[0];   // [4,4096,64]
    const float* M    = (const float*)d_in[1];   // [4,4096,32]
    const float* W    = (const float*)d_in[2];   // [64,64]
    const float* bias = (const float*)d_in[3];   // [64]
    float* out = (float*)d_out;                  // [4,4096,64]

    const size_t vElems = (size_t)BATCH * SLEN * FDIM;   // 1,048,576
    const size_t mElems = (size_t)BATCH * SLEN * KDIM;   //   524,288
    const size_t rows   = (size_t)BATCH * SLEN;          //    16,384

    float*    Vf   = (float*)d_ws;
    float*    accP = Vf + vElems;                        // vElems*KSPLIT floats
    float*    lP   = accP + vElems * KSPLIT;             // rows*KSPLIT floats
    unsigned* cnt  = (unsigned*)(lP + rows * KSPLIT);    // 128 counters
    short*    Mhi  = (short*)(cnt + 128);
    short*    Mlo  = Mhi + mElems;
    short*    Vt   = Mlo + mElems;

    prep<<<dim3(SLEN / 16, BATCH), 256, 0, stream>>>(
        (const float4*)M, (ushort4*)Mhi, (ushort4*)Mlo,
        (const float4*)X, (const float4*)W, (float4*)Vf, Vt, cnt);

    attn_mfma<<<dim3((SLEN / 128) * BATCH * KSPLIT), 256, 0, stream>>>(
        Mhi, Mlo, Vt, accP, lP, cnt,
        (const float4*)Vf, (const float4*)bias, (float4*)out);
}

// Round 5
// 108.424 us; speedup vs baseline: 1.9512x; 1.9512x over previous
//
#include <hip/hip_runtime.h>
#include <cstdint>

#define BATCH  4
#define SLEN   4096
#define FDIM   64
#define KDIM   32
#define KSPLIT 4
#define CHUNK  (SLEN / KSPLIT)   // 1024
#define NSTEP  (CHUNK / 64)      // 16 (64 keys per step)
#define VSTRIDE 76               // shorts; 152B row stride -> 2-way banks on b64

// sqrt(log2(e)): M is pre-scaled so QK^T scores come out log2e-scaled and
// exp(relu(s)) == exp2(relu(s_scaled)) -> bare v_exp_f32.
#define MSCALE 1.2011224087864498f

typedef __attribute__((ext_vector_type(8))) short bf16x8;
typedef __attribute__((ext_vector_type(4))) short bf16x4;
typedef __attribute__((ext_vector_type(4))) float f32x4;

#if __has_builtin(__builtin_amdgcn_exp2f)
#define EXP2(x) __builtin_amdgcn_exp2f(x)
#else
#define EXP2(x) exp2f(x)
#endif

static __device__ __forceinline__ short f2bf(float f) {
    union { float f; unsigned u; } v; v.f = f;
    unsigned r = v.u + 0x7fffu + ((v.u >> 16) & 1u);   // RNE
    return (short)(r >> 16);
}
static __device__ __forceinline__ float bf2f(short s) {
    union { unsigned u; float f; } v;
    v.u = ((unsigned)(unsigned short)s) << 16;
    return v.f;
}
// HW packed f32->bf16 (RNE), 1 instruction: lo16 = bf16(a), hi16 = bf16(b).
static __device__ __forceinline__ unsigned cvt_pk_bf16(float a, float b) {
    unsigned r;
    asm("v_cvt_pk_bf16_f32 %0, %1, %2" : "=v"(r) : "v"(a), "v"(b));
    return r;
}

// ---------------------------------------------------------------------------
// Fused prep: (a) M*MSCALE -> bf16 hi/lo Dekker split, (b) V = X@W (fp32),
// (c) Vt[b][f][s] = bf16(V[b][s][f]).  Grid (256,4) = 1024 blocks.
// ---------------------------------------------------------------------------
__global__ __launch_bounds__(256) void prep(const float4* __restrict__ M4,
                                            ushort4* __restrict__ H4,
                                            ushort4* __restrict__ L4,
                                            const float4* __restrict__ X4,
                                            const float4* __restrict__ W4,
                                            float4* __restrict__ V4,
                                            short* __restrict__ Vt) {
    const int tid = threadIdx.x;
    const int blk = blockIdx.y * gridDim.x + blockIdx.x;   // 0..1023
    // --- (a) scaled split of M: 1 float4 per thread, first 512 blocks ---
    if (blk < (BATCH * SLEN * KDIM) / (4 * 256)) {         // 512
        int i = blk * 256 + tid;
        float4 m = M4[i];
        float mx = m.x * MSCALE, my = m.y * MSCALE;
        float mz = m.z * MSCALE, mw = m.w * MSCALE;
        ushort4 h, l;
        h.x = (unsigned short)f2bf(mx); l.x = (unsigned short)f2bf(mx - bf2f((short)h.x));
        h.y = (unsigned short)f2bf(my); l.y = (unsigned short)f2bf(my - bf2f((short)h.y));
        h.z = (unsigned short)f2bf(mz); l.z = (unsigned short)f2bf(mz - bf2f((short)h.z));
        h.w = (unsigned short)f2bf(mw); l.w = (unsigned short)f2bf(mw - bf2f((short)h.w));
        H4[i] = h; L4[i] = l;
    }
    // --- (b)+(c) XW + transpose: 16 rows per block ---
    __shared__ float t[16][68];
    const int b  = blockIdx.y;
    const int s0 = blockIdx.x * 16;
    const int r  = tid >> 4;                               // 0..15
    const int o4 = tid & 15;
    const float4* __restrict__ xr = X4 + ((size_t)b * SLEN + s0 + r) * (FDIM / 4);
    float4 acc = make_float4(0.f, 0.f, 0.f, 0.f);
#pragma unroll
    for (int f4 = 0; f4 < FDIM / 4; ++f4) {
        float4 x  = xr[f4];
        float4 w0 = W4[(f4 * 4 + 0) * 16 + o4];
        float4 w1 = W4[(f4 * 4 + 1) * 16 + o4];
        float4 w2 = W4[(f4 * 4 + 2) * 16 + o4];
        float4 w3 = W4[(f4 * 4 + 3) * 16 + o4];
        acc.x = fmaf(x.x, w0.x, fmaf(x.y, w1.x, fmaf(x.z, w2.x, fmaf(x.w, w3.x, acc.x))));
        acc.y = fmaf(x.x, w0.y, fmaf(x.y, w1.y, fmaf(x.z, w2.y, fmaf(x.w, w3.y, acc.y))));
        acc.z = fmaf(x.x, w0.z, fmaf(x.y, w1.z, fmaf(x.z, w2.z, fmaf(x.w, w3.z, acc.z))));
        acc.w = fmaf(x.x, w0.w, fmaf(x.y, w1.w, fmaf(x.z, w2.w, fmaf(x.w, w3.w, acc.w))));
    }
    V4[((size_t)b * SLEN + s0 + r) * 16 + o4] = acc;
    t[r][o4 * 4 + 0] = acc.x;
    t[r][o4 * 4 + 1] = acc.y;
    t[r][o4 * 4 + 2] = acc.z;
    t[r][o4 * 4 + 3] = acc.w;
    __syncthreads();
    const int c  = tid & 15;
    const int f0 = tid >> 4;
#pragma unroll
    for (int i2 = 0; i2 < 4; ++i2) {
        int f = f0 + i2 * 16;
        Vt[((size_t)b * FDIM + f) * SLEN + s0 + c] = f2bf(t[c][f]);
    }
}

// ---------------------------------------------------------------------------
// Attention partials. 512 blocks (2/CU), 4 waves, 128 q/block, 64 keys/step.
// Double-buffered LDS + ONE raw s_barrier per step (lgkmcnt(0) only, no vmcnt
// drain); next step's global loads issued pre-barrier stay in flight through
// the compute phase. 4 key-tiles/step: QK = 12 MFMA/tq (3 per tile, Dekker),
// PV = 8 MFMA/tq (4 fg x 2 key-groups). P packed via v_cvt_pk_bf16_f32.
// NOTE (round-4 post-mortem): do NOT fuse the combine here via agent-scope
// atomics/fences -- per-block L2 writeback+invalidate storms cost ~130us on
// this 8-XCD part. Cross-block data flow stays on a kernel-launch boundary.
// ---------------------------------------------------------------------------
__global__ __launch_bounds__(256, 2) void attn_mfma(const short* __restrict__ Mhi,
                                                    const short* __restrict__ Mlo,
                                                    const short* __restrict__ Vt,
                                                    float* __restrict__ accP,
                                                    float* __restrict__ lP) {
    const int bid  = blockIdx.x;                 // 512 blocks
    const int slab = (bid & 7) + 8 * (bid >> 8); // 0..15, XCD-local
    const int qblk = (bid >> 3) & 31;
    const int b    = slab >> 2;
    const int ks   = slab & 3;

    const int tid  = threadIdx.x;
    const int wave = tid >> 6;
    const int lane = tid & 63;
    const int col  = lane & 15;
    const int quad = lane >> 4;
    const int qbase = qblk * 128 + wave * 32;
    const int k0    = ks * CHUNK;

    const short* __restrict__ Mbh = Mhi + (size_t)b * SLEN * KDIM;
    const short* __restrict__ Mbl = Mlo + (size_t)b * SLEN * KDIM;
    const short* __restrict__ Vb  = Vt  + (size_t)b * FDIM * SLEN;

    __shared__ short khi[2][64 * 40];            // key rows, 80 B stride
    __shared__ short klo[2][64 * 40];
    __shared__ short vsh[2][64 * VSTRIDE];       // f rows, 152 B stride

    // Q fragments (B-operand: n = q = col, k = quad*8+j).
    bf16x8 Qh[2], Ql[2];
#pragma unroll
    for (int tq = 0; tq < 2; ++tq) {
        int qo = (qbase + tq * 16 + col) * KDIM + quad * 8;
        Qh[tq] = *(const bf16x8*)(Mbh + qo);
        Ql[tq] = *(const bf16x8*)(Mbl + qo);
    }

    f32x4 accf[2][4];
#pragma unroll
    for (int tq = 0; tq < 2; ++tq)
#pragma unroll
        for (int fg = 0; fg < 4; ++fg) accf[tq][fg] = (f32x4){0.f, 0.f, 0.f, 0.f};
    float lacc[2] = {0.f, 0.f};

    // Staging: tid<128 -> khi, else klo; each thread 2x16B (one 64-key tile =
    // 64 rows x 64 B per half). V: all 256 threads, 2x16B (64 f x 128 B).
    const int krow = (tid & 127) >> 1;           // 0..63
    const int kp   = tid & 1;
    const int vrow = tid >> 2;                   // 0..63
    const int vp   = tid & 3;
    const short* __restrict__ Msrc = (tid < 128) ? Mbh : Mbl;
    const int kg0 = krow * KDIM + (kp * 2 + 0) * 8;
    const int kg1 = krow * KDIM + (kp * 2 + 1) * 8;
    const int kl0 = krow * 40 + (kp * 2 + 0) * 8;
    const int kl1 = krow * 40 + (kp * 2 + 1) * 8;
    const int vl0 = vrow * VSTRIDE + (vp + 0) * 8;
    const int vl1 = vrow * VSTRIDE + (vp + 4) * 8;

    // Prologue loads for step 0.
    bf16x8 ksA = *(const bf16x8*)(Msrc + (size_t)k0 * KDIM + kg0);
    bf16x8 ksB = *(const bf16x8*)(Msrc + (size_t)k0 * KDIM + kg1);
    bf16x8 vsA = *(const bf16x8*)(Vb + (size_t)vrow * SLEN + k0 + (vp + 0) * 8);
    bf16x8 vsB = *(const bf16x8*)(Vb + (size_t)vrow * SLEN + k0 + (vp + 4) * 8);

#pragma unroll 1
    for (int step = 0; step < NSTEP; ++step) {
        const int cur = step & 1;
        short* __restrict__ kdst = (tid < 128) ? khi[cur] : klo[cur];
        *(bf16x8*)(kdst + kl0)     = ksA;        // waits vmcnt for own loads
        *(bf16x8*)(kdst + kl1)     = ksB;
        *(bf16x8*)(vsh[cur] + vl0) = vsA;
        *(bf16x8*)(vsh[cur] + vl1) = vsB;
        if (step + 1 < NSTEP) {                  // next-step loads fly across
            int kt = k0 + (step + 1) * 64;       // the barrier
            ksA = *(const bf16x8*)(Msrc + (size_t)kt * KDIM + kg0);
            ksB = *(const bf16x8*)(Msrc + (size_t)kt * KDIM + kg1);
            vsA = *(const bf16x8*)(Vb + (size_t)vrow * SLEN + kt + (vp + 0) * 8);
            vsB = *(const bf16x8*)(Vb + (size_t)vrow * SLEN + kt + (vp + 4) * 8);
        }
        asm volatile("s_waitcnt lgkmcnt(0)" ::: "memory");  // ds_writes visible
        __builtin_amdgcn_s_barrier();                       // NO vmcnt drain
        __builtin_amdgcn_sched_barrier(0);

        const short* __restrict__ kh = khi[cur];
        const short* __restrict__ kl = klo[cur];
        const short* __restrict__ vv = vsh[cur];

        // K A-frags: tile t = keys t*16..t*16+15, m = col within tile.
        bf16x8 Kh[4], Kl[4];
#pragma unroll
        for (int t = 0; t < 4; ++t) {
            Kh[t] = *(const bf16x8*)(kh + (t * 16 + col) * 40 + quad * 8);
            Kl[t] = *(const bf16x8*)(kl + (t * 16 + col) * 40 + quad * 8);
        }
        // V B-frags per fg, key-group g (32 keys): j<4 -> key g*32+quad*4+j,
        // j>=4 -> key g*32+16+quad*4+(j-4).
        bf16x8 Vg[4][2];
#pragma unroll
        for (int fg = 0; fg < 4; ++fg)
#pragma unroll
            for (int g = 0; g < 2; ++g) {
                const short* vp_ = vv + (fg * 16 + col) * VSTRIDE + g * 32 + quad * 4;
                bf16x4 vlo = *(const bf16x4*)(vp_);
                bf16x4 vhi = *(const bf16x4*)(vp_ + 16);
                Vg[fg][g] = __builtin_shufflevector(vlo, vhi, 0, 1, 2, 3, 4, 5, 6, 7);
            }

        __builtin_amdgcn_s_setprio(1);
#pragma unroll
        for (int tq = 0; tq < 2; ++tq) {
            f32x4 c[4];
#pragma unroll
            for (int t = 0; t < 4; ++t) {
                f32x4 z = (f32x4){0.f, 0.f, 0.f, 0.f};
                c[t] = __builtin_amdgcn_mfma_f32_16x16x32_bf16(Kh[t], Ql[tq], z, 0, 0, 0);
                c[t] = __builtin_amdgcn_mfma_f32_16x16x32_bf16(Kl[t], Qh[tq], c[t], 0, 0, 0);
                c[t] = __builtin_amdgcn_mfma_f32_16x16x32_bf16(Kh[t], Qh[tq], c[t], 0, 0, 0);
            }
            float e[16];
#pragma unroll
            for (int t = 0; t < 4; ++t) {
                e[t * 4 + 0] = EXP2(fmaxf(c[t][0], 0.f));
                e[t * 4 + 1] = EXP2(fmaxf(c[t][1], 0.f));
                e[t * 4 + 2] = EXP2(fmaxf(c[t][2], 0.f));
                e[t * 4 + 3] = EXP2(fmaxf(c[t][3], 0.f));
            }
            lacc[tq] += (((e[0] + e[1]) + (e[2] + e[3])) + ((e[4] + e[5]) + (e[6] + e[7])))
                      + (((e[8] + e[9]) + (e[10] + e[11])) + ((e[12] + e[13]) + (e[14] + e[15])));

            union { unsigned u[4]; bf16x8 v; } pa0, pa1;
            pa0.u[0] = cvt_pk_bf16(e[0],  e[1]);
            pa0.u[1] = cvt_pk_bf16(e[2],  e[3]);
            pa0.u[2] = cvt_pk_bf16(e[4],  e[5]);
            pa0.u[3] = cvt_pk_bf16(e[6],  e[7]);
            pa1.u[0] = cvt_pk_bf16(e[8],  e[9]);
            pa1.u[1] = cvt_pk_bf16(e[10], e[11]);
            pa1.u[2] = cvt_pk_bf16(e[12], e[13]);
            pa1.u[3] = cvt_pk_bf16(e[14], e[15]);

#pragma unroll
            for (int fg = 0; fg < 4; ++fg) {
                accf[tq][fg] = __builtin_amdgcn_mfma_f32_16x16x32_bf16(
                    pa0.v, Vg[fg][0], accf[tq][fg], 0, 0, 0);
                accf[tq][fg] = __builtin_amdgcn_mfma_f32_16x16x32_bf16(
                    pa1.v, Vg[fg][1], accf[tq][fg], 0, 0, 0);
            }
        }
        __builtin_amdgcn_s_setprio(0);
    }

    // Epilogue: C[m=q][n=f]: row q = quad*4+j, col f = fg*16+col.
#pragma unroll
    for (int tq = 0; tq < 2; ++tq) {
#pragma unroll
        for (int j = 0; j < 4; ++j) {
            int q = qbase + tq * 16 + quad * 4 + j;
            size_t base = ((size_t)b * SLEN + q) * KSPLIT + ks;
            float* __restrict__ op = accP + base * FDIM;
#pragma unroll
            for (int fg = 0; fg < 4; ++fg)
                op[fg * 16 + col] = accf[tq][fg][j];
        }
        float lv = lacc[tq];
        lv += __shfl_xor(lv, 16);
        lv += __shfl_xor(lv, 32);
        if (quad == 0) {
            int q = qbase + tq * 16 + col;
            lP[((size_t)b * SLEN + q) * KSPLIT + ks] = lv;
        }
    }
}

// ---------------------------------------------------------------------------
// out = V + (sum acc_i)/(sum l_i) + bias, float4; lP is one float4 per row.
// ---------------------------------------------------------------------------
__global__ __launch_bounds__(256) void combine_kernel(const float4* __restrict__ V4,
                                                      const float4* __restrict__ accP4,
                                                      const float4* __restrict__ lP4,
                                                      const float4* __restrict__ bias4,
                                                      float4* __restrict__ out4) {
    int i  = blockIdx.x * 256 + threadIdx.x;     // [0, B*S*16)
    int o4 = i & 15;
    int row = i >> 4;
    float nx = 0.f, ny = 0.f, nz = 0.f, nw = 0.f;
#pragma unroll
    for (int k = 0; k < KSPLIT; ++k) {
        float4 a = accP4[((size_t)row * KSPLIT + k) * 16 + o4];
        nx += a.x; ny += a.y; nz += a.z; nw += a.w;
    }
    float4 l = lP4[row];
    float den = (l.x + l.y) + (l.z + l.w);
    float r = 1.f / den;
    float4 v = V4[i];
    float4 bb = bias4[o4];
    float4 o;
    o.x = v.x + nx * r + bb.x;
    o.y = v.y + ny * r + bb.y;
    o.z = v.z + nz * r + bb.z;
    o.w = v.w + nw * r + bb.w;
    out4[i] = o;
}

// ---------------------------------------------------------------------------
extern "C" void kernel_launch(void* const* d_in, const int* in_sizes, int n_in,
                              void* d_out, int out_size, void* d_ws, size_t ws_size,
                              hipStream_t stream) {
    const float* X    = (const float*)d_in[0];   // [4,4096,64]
    const float* M    = (const float*)d_in[1];   // [4,4096,32]
    const float* W    = (const float*)d_in[2];   // [64,64]
    const float* bias = (const float*)d_in[3];   // [64]
    float* out = (float*)d_out;                  // [4,4096,64]

    const size_t vElems = (size_t)BATCH * SLEN * FDIM;   // 1,048,576
    const size_t mElems = (size_t)BATCH * SLEN * KDIM;   //   524,288
    const size_t rows   = (size_t)BATCH * SLEN;          //    16,384

    float* Vf   = (float*)d_ws;
    float* accP = Vf + vElems;
    float* lP   = accP + vElems * KSPLIT;
    short* Mhi  = (short*)(lP + rows * KSPLIT);
    short* Mlo  = Mhi + mElems;
    short* Vt   = Mlo + mElems;

    prep<<<dim3(SLEN / 16, BATCH), 256, 0, stream>>>(
        (const float4*)M, (ushort4*)Mhi, (ushort4*)Mlo,
        (const float4*)X, (const float4*)W, (float4*)Vf, Vt);

    attn_mfma<<<dim3((SLEN / 128) * BATCH * KSPLIT), 256, 0, stream>>>(
        Mhi, Mlo, Vt, accP, lP);

    combine_kernel<<<(int)(vElems / 1024), 256, 0, stream>>>(
        (const float4*)Vf, (const float4*)accP, (const float4*)lP,
        (const float4*)bias, (float4*)out);
}